// Round 2
// baseline (12706.156 us; speedup 1.0000x reference)
//
#include <hip/hip_runtime.h>

// Problem dims
#define HS_   1024
#define G4_   4096
#define EMB_  512
#define B_    64
#define S_    512
#define DIM_  128

typedef __attribute__((ext_vector_type(8))) short short8;
typedef __attribute__((ext_vector_type(4))) float floatx4;

__device__ __forceinline__ unsigned short f2bf(float f){
  union { float f; unsigned u; } v; v.f = f;
  unsigned r = v.u + 0x7FFFu + ((v.u >> 16) & 1u);   // RNE
  return (unsigned short)(r >> 16);
}
__device__ __forceinline__ float bf2f(unsigned short b){
  union { unsigned u; float f; } v; v.u = ((unsigned)b) << 16; return v.f;
}
// hi/lo split: f = bf2f(hi) + bf2f(lo) + O(f * 2^-18)
__device__ __forceinline__ void splitbf(float f, unsigned short& hi, unsigned short& lo){
  unsigned short h = f2bf(f);
  hi = h;
  lo = f2bf(f - bf2f(h));
}
__device__ __forceinline__ float sigm_f(float x){ return 1.0f/(1.0f + __expf(-x)); }
__device__ __forceinline__ float tanh_f(float x){ return 1.0f - 2.0f/(1.0f + __expf(2.0f*x)); }

// ---------------------------------------------------------------------------
// Kernel 1: x = event@Ve + 2*vc@Vc + 2*tanh(vn@Vn)  -> fp32 [32768][512]
// 128x128 tiles, split-bf16 3-pass 16x16x32 MFMA (~fp32 accuracy).
// ---------------------------------------------------------------------------
__global__ __launch_bounds__(256) void k_embed(
    const float* __restrict__ ev, const float* __restrict__ vcp, const float* __restrict__ vnp,
    const float* __restrict__ Ve, const float* __restrict__ Vc, const float* __restrict__ Vn,
    float* __restrict__ xout)
{
  __shared__ unsigned short a_hi[128][40], a_lo[128][40];
  __shared__ unsigned short b_hi[128][40], b_lo[128][40];   // transposed: [n][k]
  const int tid  = threadIdx.x;
  const int lane = tid & 63;
  const int w    = tid >> 6;
  const int wr = w >> 1, wc = w & 1;
  const int mt = blockIdx.x >> 2;
  const int nt = blockIdx.x & 3;
  const int m0 = mt * 128, n0 = nt * 128;
  const int fr = lane & 15;
  const int fk = (lane >> 4) * 8;

  floatx4 acc[4][4];
  #pragma unroll
  for (int i=0;i<4;i++)
    #pragma unroll
    for (int j=0;j<4;j++)
      acc[i][j] = (floatx4){0.f,0.f,0.f,0.f};

  auto do_stage = [&](const float* A, int lda, const float* Bm, int kBase, float bscale){
    __syncthreads();
    #pragma unroll
    for (int c=0;c<4;c++){                      // A tile [128 rows][32 k], split hi/lo
      int flat = tid*16 + c*4;
      int r = flat >> 5, kk = flat & 31;
      float4 v = *(const float4*)(A + (m0+r)*lda + kBase + kk);
      splitbf(v.x, a_hi[r][kk+0], a_lo[r][kk+0]);
      splitbf(v.y, a_hi[r][kk+1], a_lo[r][kk+1]);
      splitbf(v.z, a_hi[r][kk+2], a_lo[r][kk+2]);
      splitbf(v.w, a_hi[r][kk+3], a_lo[r][kk+3]);
    }
    #pragma unroll
    for (int c=0;c<4;c++){                      // B tile [32 k][128 n] -> transposed, split
      int flat = tid*16 + c*4;
      int k = flat >> 7, nn = flat & 127;
      float4 v = *(const float4*)(Bm + (kBase+k)*EMB_ + n0 + nn);
      splitbf(v.x * bscale, b_hi[nn+0][k], b_lo[nn+0][k]);
      splitbf(v.y * bscale, b_hi[nn+1][k], b_lo[nn+1][k]);
      splitbf(v.z * bscale, b_hi[nn+2][k], b_lo[nn+2][k]);
      splitbf(v.w * bscale, b_hi[nn+3][k], b_lo[nn+3][k]);
    }
    __syncthreads();
    short8 ah[4], al[4], bh[4], bl[4];
    #pragma unroll
    for (int mi=0;mi<4;mi++){
      ah[mi] = *(const short8*)&a_hi[wr*64 + mi*16 + fr][fk];
      al[mi] = *(const short8*)&a_lo[wr*64 + mi*16 + fr][fk];
    }
    #pragma unroll
    for (int ni=0;ni<4;ni++){
      bh[ni] = *(const short8*)&b_hi[wc*64 + ni*16 + fr][fk];
      bl[ni] = *(const short8*)&b_lo[wc*64 + ni*16 + fr][fk];
    }
    #pragma unroll
    for (int mi=0;mi<4;mi++)
      #pragma unroll
      for (int ni=0;ni<4;ni++){
        floatx4 t = acc[mi][ni];
        t = __builtin_amdgcn_mfma_f32_16x16x32_bf16(al[mi], bh[ni], t, 0, 0, 0);
        t = __builtin_amdgcn_mfma_f32_16x16x32_bf16(ah[mi], bl[ni], t, 0, 0, 0);
        t = __builtin_amdgcn_mfma_f32_16x16x32_bf16(ah[mi], bh[ni], t, 0, 0, 0);
        acc[mi][ni] = t;
      }
  };

  // Phase 1: vn@Vn (K=64), then acc = 2*tanh(acc)
  do_stage(vnp, 64, Vn, 0, 1.f);
  do_stage(vnp, 64, Vn, 32, 1.f);
  #pragma unroll
  for (int mi=0;mi<4;mi++)
    #pragma unroll
    for (int ni=0;ni<4;ni++)
      #pragma unroll
      for (int r=0;r<4;r++)
        acc[mi][ni][r] = 2.f * tanh_f(acc[mi][ni][r]);
  // Phase 2: + event@Ve (K=1024)
  for (int ks=0; ks<32; ks++) do_stage(ev, 1024, Ve, ks*32, 1.f);
  // Phase 3: + vc@(2*Vc) (K=512)
  for (int ks=0; ks<16; ks++) do_stage(vcp, 512, Vc, ks*32, 2.f);

  // Epilogue fp32: C layout col=lane&15, row=(lane>>4)*4+r
  #pragma unroll
  for (int mi=0;mi<4;mi++)
    #pragma unroll
    for (int ni=0;ni<4;ni++){
      int col = n0 + wc*64 + ni*16 + fr;
      #pragma unroll
      for (int r=0;r<4;r++){
        int row = m0 + wr*64 + mi*16 + (lane>>4)*4 + r;
        xout[row*EMB_ + col] = acc[mi][ni][r];
      }
    }
}

// ---------------------------------------------------------------------------
// Kernel 2: xW = x@Wx + bias -> bf16, COLUMN-PERMUTED layout:
//   p = blk*16 + gate*4 + within,  source col n(p) = gate*1024 + blk*4 + within
// Split-bf16 3-pass MFMA; x input fp32; bf16 output is safe (relative error).
// ---------------------------------------------------------------------------
__global__ __launch_bounds__(256) void k_xw(
    const float* __restrict__ x, const float* __restrict__ Wx,
    const float* __restrict__ bias, unsigned short* __restrict__ xwp)
{
  __shared__ unsigned short a_hi[128][40], a_lo[128][40];
  __shared__ unsigned short b_hi[128][40], b_lo[128][40];
  const int tid  = threadIdx.x;
  const int lane = tid & 63;
  const int w    = tid >> 6;
  const int wr = w >> 1, wc = w & 1;
  const int mt = blockIdx.x >> 5;
  const int nt = blockIdx.x & 31;
  const int m0 = mt * 128, p0 = nt * 128;
  const int fr = lane & 15;
  const int fk = (lane >> 4) * 8;

  floatx4 acc[4][4];
  #pragma unroll
  for (int i=0;i<4;i++)
    #pragma unroll
    for (int j=0;j<4;j++)
      acc[i][j] = (floatx4){0.f,0.f,0.f,0.f};

  for (int ks=0; ks<16; ks++){
    const int kBase = ks*32;
    __syncthreads();
    #pragma unroll
    for (int c=0;c<4;c++){                      // A tile fp32 [128][32], split
      int flat = tid*16 + c*4;
      int r = flat >> 5, kk = flat & 31;
      float4 v = *(const float4*)(x + (m0+r)*EMB_ + kBase + kk);
      splitbf(v.x, a_hi[r][kk+0], a_lo[r][kk+0]);
      splitbf(v.y, a_hi[r][kk+1], a_lo[r][kk+1]);
      splitbf(v.z, a_hi[r][kk+2], a_lo[r][kk+2]);
      splitbf(v.w, a_hi[r][kk+3], a_lo[r][kk+3]);
    }
    #pragma unroll
    for (int c=0;c<4;c++){                      // B permuted gather, split
      int flat = tid*16 + c*4;
      int k = flat >> 7, pc = flat & 127;
      int p = p0 + pc;
      int nbase = ((p>>2)&3)*HS_ + (p>>4)*4;
      float4 v = *(const float4*)(Wx + (kBase+k)*G4_ + nbase);
      splitbf(v.x, b_hi[pc+0][k], b_lo[pc+0][k]);
      splitbf(v.y, b_hi[pc+1][k], b_lo[pc+1][k]);
      splitbf(v.z, b_hi[pc+2][k], b_lo[pc+2][k]);
      splitbf(v.w, b_hi[pc+3][k], b_lo[pc+3][k]);
    }
    __syncthreads();
    short8 ah[4], al[4], bh[4], bl[4];
    #pragma unroll
    for (int mi=0;mi<4;mi++){
      ah[mi] = *(const short8*)&a_hi[wr*64 + mi*16 + fr][fk];
      al[mi] = *(const short8*)&a_lo[wr*64 + mi*16 + fr][fk];
    }
    #pragma unroll
    for (int ni=0;ni<4;ni++){
      bh[ni] = *(const short8*)&b_hi[wc*64 + ni*16 + fr][fk];
      bl[ni] = *(const short8*)&b_lo[wc*64 + ni*16 + fr][fk];
    }
    #pragma unroll
    for (int mi=0;mi<4;mi++)
      #pragma unroll
      for (int ni=0;ni<4;ni++){
        floatx4 t = acc[mi][ni];
        t = __builtin_amdgcn_mfma_f32_16x16x32_bf16(al[mi], bh[ni], t, 0, 0, 0);
        t = __builtin_amdgcn_mfma_f32_16x16x32_bf16(ah[mi], bl[ni], t, 0, 0, 0);
        t = __builtin_amdgcn_mfma_f32_16x16x32_bf16(ah[mi], bh[ni], t, 0, 0, 0);
        acc[mi][ni] = t;
      }
  }

  #pragma unroll
  for (int ni=0;ni<4;ni++){
    int p = p0 + wc*64 + ni*16 + fr;
    int n = ((p>>2)&3)*HS_ + (p>>4)*4 + (p&3);
    float bv = bias[n];
    #pragma unroll
    for (int mi=0;mi<4;mi++){
      #pragma unroll
      for (int r=0;r<4;r++){
        int row = m0 + wr*64 + mi*16 + (lane>>4)*4 + r;
        xwp[row*G4_ + p] = f2bf(acc[mi][ni][r] + bv);
      }
    }
  }
}

// ---------------------------------------------------------------------------
// Kernel 3: persistent cooperative LSTM scan + final h@W_lin+b_lin.
// 256 blocks x 256 threads, 1 block/CU. Block owns 4 h-cols (16 gate-cols).
// Wh slice pre-packed into 32 register-resident bf16 B-fragments.
// ---------------------------------------------------------------------------
__device__ __forceinline__ void grid_barrier(int* cnt, int target){
  __syncthreads();                               // drains this block's stores
  if (threadIdx.x == 0){
    __hip_atomic_fetch_add(cnt, 1, __ATOMIC_RELEASE, __HIP_MEMORY_SCOPE_AGENT);
    while (__hip_atomic_load(cnt, __ATOMIC_RELAXED, __HIP_MEMORY_SCOPE_AGENT) < target){
      __builtin_amdgcn_s_sleep(1);
    }
  }
  __syncthreads();
  __builtin_amdgcn_fence(__ATOMIC_ACQUIRE, "agent");   // invalidate stale h lines
}

__global__ __launch_bounds__(256, 1) void k_lstm(
    const unsigned short* __restrict__ xwp, unsigned short* __restrict__ hbuf,
    int* __restrict__ cnt,
    const float* __restrict__ Wh, const float* __restrict__ Wc,
    const float* __restrict__ Wlin, const float* __restrict__ blin,
    float* __restrict__ out)
{
  __shared__ float xw_lds[64][16];
  __shared__ float gbuf[64][17];
  __shared__ float red[256];
  const int tid  = threadIdx.x;
  const int lane = tid & 63;
  const int w    = tid >> 6;
  const int phys = blockIdx.x;
  const int blk  = (phys & 7)*32 + (phys >> 3);  // XCD-grouped logical block id
  const int c0   = blk * 4;                      // first owned h-column

  // Pack Wh[:, 16 gate cols] into 32 register B-fragments (bf16).
  // B layout: n=lane&15 (local col = gate*4+within), k=(lane>>4)*8+j
  short8 wfrag[32];
  {
    const int ncol = lane & 15;
    const int gcol = (ncol >> 2)*HS_ + c0 + (ncol & 3);
    const int kr0  = (lane >> 4) * 8;
    #pragma unroll
    for (int ks=0; ks<32; ks++){
      short8 v;
      #pragma unroll
      for (int j=0;j<8;j++)
        v[j] = (short)f2bf(Wh[(ks*32 + kr0 + j)*G4_ + gcol]);
      wfrag[ks] = v;
    }
  }

  // Per-thread elementwise assignment: (batch row, owned col)
  const int erow = tid >> 2, ej = tid & 3;
  const int hcol = c0 + ej;
  const float wc0 = Wc[hcol], wc1 = Wc[HS_ + hcol], wc2 = Wc[2*HS_ + hcol];
  float c_reg = 0.f;

  // A-fragment addressing: row = batch (wave covers 16 rows), k contiguous 8
  const int arow  = w*16 + (lane & 15);
  const int akoff = (lane >> 4) * 8;
  const int xr = tid & 63, xg = tid >> 6;       // xW loader mapping

  for (int t=0; t<S_; t++){
    const unsigned short* hin  = hbuf + (t & 1)      * B_ * HS_;
    unsigned short*       hout = hbuf + ((t+1) & 1)  * B_ * HS_;

    // Load this step's xW chunk (16 bf16 per row, 8B per thread) into LDS
    {
      ushort4 v = *(const ushort4*)(xwp + (xr*S_ + t)*G4_ + blk*16 + xg*4);
      xw_lds[xr][xg*4+0] = bf2f(v.x); xw_lds[xr][xg*4+1] = bf2f(v.y);
      xw_lds[xr][xg*4+2] = bf2f(v.z); xw_lds[xr][xg*4+3] = bf2f(v.w);
    }

    // h @ Wh_slice : [64x1024]@[1024x16], 32 MFMAs over 4 accumulator chains
    floatx4 a0 = (floatx4){0.f,0.f,0.f,0.f}, a1 = a0, a2 = a0, a3 = a0;
    const unsigned short* ap = hin + arow*HS_ + akoff;
    #pragma unroll
    for (int ks=0; ks<32; ks+=4){
      short8 f0 = *(const short8*)(ap + (ks+0)*32);
      short8 f1 = *(const short8*)(ap + (ks+1)*32);
      short8 f2 = *(const short8*)(ap + (ks+2)*32);
      short8 f3 = *(const short8*)(ap + (ks+3)*32);
      a0 = __builtin_amdgcn_mfma_f32_16x16x32_bf16(f0, wfrag[ks+0], a0, 0,0,0);
      a1 = __builtin_amdgcn_mfma_f32_16x16x32_bf16(f1, wfrag[ks+1], a1, 0,0,0);
      a2 = __builtin_amdgcn_mfma_f32_16x16x32_bf16(f2, wfrag[ks+2], a2, 0,0,0);
      a3 = __builtin_amdgcn_mfma_f32_16x16x32_bf16(f3, wfrag[ks+3], a3, 0,0,0);
    }
    floatx4 acc = a0 + a1 + a2 + a3;

    // Scatter C to LDS: col=lane&15, row=w*16+(lane>>4)*4+r
    {
      const int gr = w*16 + (lane>>4)*4;
      const int gc = lane & 15;
      gbuf[gr+0][gc] = acc[0];
      gbuf[gr+1][gc] = acc[1];
      gbuf[gr+2][gc] = acc[2];
      gbuf[gr+3][gc] = acc[3];
    }
    __syncthreads();

    // Elementwise LSTM cell (fp32 state in registers; peephole uses OLD c)
    {
      float gi = gbuf[erow][ 0+ej] + xw_lds[erow][ 0+ej];
      float gf = gbuf[erow][ 4+ej] + xw_lds[erow][ 4+ej];
      float gg = gbuf[erow][ 8+ej] + xw_lds[erow][ 8+ej];
      float go = gbuf[erow][12+ej] + xw_lds[erow][12+ej];
      float iv = sigm_f(gi + c_reg*wc0);
      float fv = sigm_f(gf + c_reg*wc1);
      float gv = tanh_f(gg);
      float ov = sigm_f(go + c_reg*wc2);
      float cn = fv*c_reg + iv*gv;
      float hn = ov*tanh_f(cn);
      c_reg = cn;
      hout[erow*HS_ + hcol] = f2bf(hn);
    }

    grid_barrier(cnt, 256*(t+1));
  }

  // Final: out[b][d] = sum_k h512[b][k]*Wlin[k][d] + blin[d]   (h512 in hbuf[0])
  {
    const unsigned short* hfin = hbuf;          // after 512 steps, final h is buffer 0
    const int b  = phys >> 2;
    const int cg = phys & 3;
    const int cl = tid & 31, kc = tid >> 5;
    const int col = cg*32 + cl;
    float s = 0.f;
    for (int k = kc*128; k < kc*128 + 128; k++)
      s += bf2f(hfin[b*HS_ + k]) * Wlin[k*DIM_ + col];
    red[tid] = s;
    __syncthreads();
    if (tid < 32){
      float tot = blin[cg*32 + tid];
      #pragma unroll
      for (int q=0;q<8;q++) tot += red[q*32 + tid];
      out[b*DIM_ + cg*32 + tid] = tot;
    }
  }
}

// ---------------------------------------------------------------------------
extern "C" void kernel_launch(void* const* d_in, const int* in_sizes, int n_in,
                              void* d_out, int out_size, void* d_ws, size_t ws_size,
                              hipStream_t stream)
{
  (void)in_sizes; (void)n_in; (void)out_size; (void)ws_size;
  const float* ev   = (const float*)d_in[0];
  const float* vcp  = (const float*)d_in[1];
  const float* vnp  = (const float*)d_in[2];
  const float* Ve   = (const float*)d_in[3];
  const float* Vc   = (const float*)d_in[4];
  const float* Vn   = (const float*)d_in[5];
  const float* Wx   = (const float*)d_in[6];
  const float* Wh   = (const float*)d_in[7];
  const float* Wc   = (const float*)d_in[8];
  const float* bias = (const float*)d_in[9];
  const float* Wl   = (const float*)d_in[10];
  const float* bl   = (const float*)d_in[11];
  float* outp = (float*)d_out;

  // ws layout: x fp32 (64MB) | xWP bf16 (256MB) | h double-buffer (256KB) | counter
  char* ws = (char*)d_ws;
  float*          xf   = (float*)ws;
  unsigned short* xwp  = (unsigned short*)(ws + (size_t)67108864);
  unsigned short* hbuf = (unsigned short*)(ws + (size_t)67108864 + (size_t)268435456);
  int* cnt             = (int*)(ws + (size_t)67108864 + (size_t)268435456 + (size_t)262144);

  // h0 = 0 and barrier counter = 0 (ws is re-poisoned before every launch)
  hipMemsetAsync(hbuf, 0, 262144 + 256, stream);

  k_embed<<<dim3(1024), dim3(256), 0, stream>>>(ev, vcp, vnp, Ve, Vc, Vn, xf);
  k_xw<<<dim3(8192), dim3(256), 0, stream>>>(xf, Wx, bias, xwp);

  const unsigned short* a0 = xwp;
  unsigned short* a1 = hbuf;
  int* a2 = cnt;
  const float* a3 = Wh; const float* a4 = Wc;
  const float* a5 = Wl; const float* a6 = bl;
  float* a7 = outp;
  void* args[] = {&a0, &a1, &a2, &a3, &a4, &a5, &a6, &a7};
  hipLaunchCooperativeKernel((void*)k_lstm, dim3(256), dim3(256), args, 0, stream);
}

// Round 3
// 7349.368 us; speedup vs baseline: 1.7289x; 1.7289x over previous
//
#include <hip/hip_runtime.h>

// Problem dims
#define HS_   1024
#define G4_   4096
#define EMB_  512
#define B_    64
#define S_    512
#define DIM_  128

typedef __attribute__((ext_vector_type(8))) short short8;
typedef __attribute__((ext_vector_type(4))) float floatx4;

__device__ __forceinline__ unsigned short f2bf(float f){
  union { float f; unsigned u; } v; v.f = f;
  unsigned r = v.u + 0x7FFFu + ((v.u >> 16) & 1u);   // RNE
  return (unsigned short)(r >> 16);
}
__device__ __forceinline__ float bf2f(unsigned short b){
  union { unsigned u; float f; } v; v.u = ((unsigned)b) << 16; return v.f;
}
// hi/lo split: f = bf2f(hi) + bf2f(lo) + O(f * 2^-18)
__device__ __forceinline__ void splitbf(float f, unsigned short& hi, unsigned short& lo){
  unsigned short h = f2bf(f);
  hi = h;
  lo = f2bf(f - bf2f(h));
}
__device__ __forceinline__ float sigm_f(float x){ return 1.0f/(1.0f + __expf(-x)); }
__device__ __forceinline__ float tanh_f(float x){ return 1.0f - 2.0f/(1.0f + __expf(2.0f*x)); }

// 16B fragment via two 8B relaxed agent-scope atomic loads (sc1: bypass local L2,
// served at the cross-XCD coherence point / L3).
__device__ __forceinline__ short8 ldfrag_sc1(const unsigned long long* p){
  union { unsigned long long q[2]; short8 s; } u;
  u.q[0] = __hip_atomic_load(p,     __ATOMIC_RELAXED, __HIP_MEMORY_SCOPE_AGENT);
  u.q[1] = __hip_atomic_load(p + 1, __ATOMIC_RELAXED, __HIP_MEMORY_SCOPE_AGENT);
  return u.s;
}

// ---------------------------------------------------------------------------
// Kernel 1: x = event@Ve + 2*vc@Vc + 2*tanh(vn@Vn)  -> fp32 [32768][512]
// 128x128 tiles, split-bf16 3-pass 16x16x32 MFMA (~fp32 accuracy).
// ---------------------------------------------------------------------------
__global__ __launch_bounds__(256) void k_embed(
    const float* __restrict__ ev, const float* __restrict__ vcp, const float* __restrict__ vnp,
    const float* __restrict__ Ve, const float* __restrict__ Vc, const float* __restrict__ Vn,
    float* __restrict__ xout)
{
  __shared__ unsigned short a_hi[128][40], a_lo[128][40];
  __shared__ unsigned short b_hi[128][40], b_lo[128][40];   // transposed: [n][k]
  const int tid  = threadIdx.x;
  const int lane = tid & 63;
  const int w    = tid >> 6;
  const int wr = w >> 1, wc = w & 1;
  const int mt = blockIdx.x >> 2;
  const int nt = blockIdx.x & 3;
  const int m0 = mt * 128, n0 = nt * 128;
  const int fr = lane & 15;
  const int fk = (lane >> 4) * 8;

  floatx4 acc[4][4];
  #pragma unroll
  for (int i=0;i<4;i++)
    #pragma unroll
    for (int j=0;j<4;j++)
      acc[i][j] = (floatx4){0.f,0.f,0.f,0.f};

  auto do_stage = [&](const float* A, int lda, const float* Bm, int kBase, float bscale){
    __syncthreads();
    #pragma unroll
    for (int c=0;c<4;c++){                      // A tile [128 rows][32 k], split hi/lo
      int flat = tid*16 + c*4;
      int r = flat >> 5, kk = flat & 31;
      float4 v = *(const float4*)(A + (m0+r)*lda + kBase + kk);
      splitbf(v.x, a_hi[r][kk+0], a_lo[r][kk+0]);
      splitbf(v.y, a_hi[r][kk+1], a_lo[r][kk+1]);
      splitbf(v.z, a_hi[r][kk+2], a_lo[r][kk+2]);
      splitbf(v.w, a_hi[r][kk+3], a_lo[r][kk+3]);
    }
    #pragma unroll
    for (int c=0;c<4;c++){                      // B tile [32 k][128 n] -> transposed, split
      int flat = tid*16 + c*4;
      int k = flat >> 7, nn = flat & 127;
      float4 v = *(const float4*)(Bm + (kBase+k)*EMB_ + n0 + nn);
      splitbf(v.x * bscale, b_hi[nn+0][k], b_lo[nn+0][k]);
      splitbf(v.y * bscale, b_hi[nn+1][k], b_lo[nn+1][k]);
      splitbf(v.z * bscale, b_hi[nn+2][k], b_lo[nn+2][k]);
      splitbf(v.w * bscale, b_hi[nn+3][k], b_lo[nn+3][k]);
    }
    __syncthreads();
    short8 ah[4], al[4], bh[4], bl[4];
    #pragma unroll
    for (int mi=0;mi<4;mi++){
      ah[mi] = *(const short8*)&a_hi[wr*64 + mi*16 + fr][fk];
      al[mi] = *(const short8*)&a_lo[wr*64 + mi*16 + fr][fk];
    }
    #pragma unroll
    for (int ni=0;ni<4;ni++){
      bh[ni] = *(const short8*)&b_hi[wc*64 + ni*16 + fr][fk];
      bl[ni] = *(const short8*)&b_lo[wc*64 + ni*16 + fr][fk];
    }
    #pragma unroll
    for (int mi=0;mi<4;mi++)
      #pragma unroll
      for (int ni=0;ni<4;ni++){
        floatx4 t = acc[mi][ni];
        t = __builtin_amdgcn_mfma_f32_16x16x32_bf16(al[mi], bh[ni], t, 0, 0, 0);
        t = __builtin_amdgcn_mfma_f32_16x16x32_bf16(ah[mi], bl[ni], t, 0, 0, 0);
        t = __builtin_amdgcn_mfma_f32_16x16x32_bf16(ah[mi], bh[ni], t, 0, 0, 0);
        acc[mi][ni] = t;
      }
  };

  // Phase 1: vn@Vn (K=64), then acc = 2*tanh(acc)
  do_stage(vnp, 64, Vn, 0, 1.f);
  do_stage(vnp, 64, Vn, 32, 1.f);
  #pragma unroll
  for (int mi=0;mi<4;mi++)
    #pragma unroll
    for (int ni=0;ni<4;ni++)
      #pragma unroll
      for (int r=0;r<4;r++)
        acc[mi][ni][r] = 2.f * tanh_f(acc[mi][ni][r]);
  // Phase 2: + event@Ve (K=1024)
  for (int ks=0; ks<32; ks++) do_stage(ev, 1024, Ve, ks*32, 1.f);
  // Phase 3: + vc@(2*Vc) (K=512)
  for (int ks=0; ks<16; ks++) do_stage(vcp, 512, Vc, ks*32, 2.f);

  // Epilogue fp32: C layout col=lane&15, row=(lane>>4)*4+r
  #pragma unroll
  for (int mi=0;mi<4;mi++)
    #pragma unroll
    for (int ni=0;ni<4;ni++){
      int col = n0 + wc*64 + ni*16 + fr;
      #pragma unroll
      for (int r=0;r<4;r++){
        int row = m0 + wr*64 + mi*16 + (lane>>4)*4 + r;
        xout[row*EMB_ + col] = acc[mi][ni][r];
      }
    }
}

// ---------------------------------------------------------------------------
// Kernel 2: xW = x@Wx + bias -> bf16, COLUMN-PERMUTED layout:
//   p = blk*16 + gate*4 + within,  source col n(p) = gate*1024 + blk*4 + within
// Split-bf16 3-pass MFMA; x input fp32; bf16 output is safe (relative error).
// ---------------------------------------------------------------------------
__global__ __launch_bounds__(256) void k_xw(
    const float* __restrict__ x, const float* __restrict__ Wx,
    const float* __restrict__ bias, unsigned short* __restrict__ xwp)
{
  __shared__ unsigned short a_hi[128][40], a_lo[128][40];
  __shared__ unsigned short b_hi[128][40], b_lo[128][40];
  const int tid  = threadIdx.x;
  const int lane = tid & 63;
  const int w    = tid >> 6;
  const int wr = w >> 1, wc = w & 1;
  const int mt = blockIdx.x >> 5;
  const int nt = blockIdx.x & 31;
  const int m0 = mt * 128, p0 = nt * 128;
  const int fr = lane & 15;
  const int fk = (lane >> 4) * 8;

  floatx4 acc[4][4];
  #pragma unroll
  for (int i=0;i<4;i++)
    #pragma unroll
    for (int j=0;j<4;j++)
      acc[i][j] = (floatx4){0.f,0.f,0.f,0.f};

  for (int ks=0; ks<16; ks++){
    const int kBase = ks*32;
    __syncthreads();
    #pragma unroll
    for (int c=0;c<4;c++){                      // A tile fp32 [128][32], split
      int flat = tid*16 + c*4;
      int r = flat >> 5, kk = flat & 31;
      float4 v = *(const float4*)(x + (m0+r)*EMB_ + kBase + kk);
      splitbf(v.x, a_hi[r][kk+0], a_lo[r][kk+0]);
      splitbf(v.y, a_hi[r][kk+1], a_lo[r][kk+1]);
      splitbf(v.z, a_hi[r][kk+2], a_lo[r][kk+2]);
      splitbf(v.w, a_hi[r][kk+3], a_lo[r][kk+3]);
    }
    #pragma unroll
    for (int c=0;c<4;c++){                      // B permuted gather, split
      int flat = tid*16 + c*4;
      int k = flat >> 7, pc = flat & 127;
      int p = p0 + pc;
      int nbase = ((p>>2)&3)*HS_ + (p>>4)*4;
      float4 v = *(const float4*)(Wx + (kBase+k)*G4_ + nbase);
      splitbf(v.x, b_hi[pc+0][k], b_lo[pc+0][k]);
      splitbf(v.y, b_hi[pc+1][k], b_lo[pc+1][k]);
      splitbf(v.z, b_hi[pc+2][k], b_lo[pc+2][k]);
      splitbf(v.w, b_hi[pc+3][k], b_lo[pc+3][k]);
    }
    __syncthreads();
    short8 ah[4], al[4], bh[4], bl[4];
    #pragma unroll
    for (int mi=0;mi<4;mi++){
      ah[mi] = *(const short8*)&a_hi[wr*64 + mi*16 + fr][fk];
      al[mi] = *(const short8*)&a_lo[wr*64 + mi*16 + fr][fk];
    }
    #pragma unroll
    for (int ni=0;ni<4;ni++){
      bh[ni] = *(const short8*)&b_hi[wc*64 + ni*16 + fr][fk];
      bl[ni] = *(const short8*)&b_lo[wc*64 + ni*16 + fr][fk];
    }
    #pragma unroll
    for (int mi=0;mi<4;mi++)
      #pragma unroll
      for (int ni=0;ni<4;ni++){
        floatx4 t = acc[mi][ni];
        t = __builtin_amdgcn_mfma_f32_16x16x32_bf16(al[mi], bh[ni], t, 0, 0, 0);
        t = __builtin_amdgcn_mfma_f32_16x16x32_bf16(ah[mi], bl[ni], t, 0, 0, 0);
        t = __builtin_amdgcn_mfma_f32_16x16x32_bf16(ah[mi], bh[ni], t, 0, 0, 0);
        acc[mi][ni] = t;
      }
  }

  #pragma unroll
  for (int ni=0;ni<4;ni++){
    int p = p0 + wc*64 + ni*16 + fr;
    int n = ((p>>2)&3)*HS_ + (p>>4)*4 + (p&3);
    float bv = bias[n];
    #pragma unroll
    for (int mi=0;mi<4;mi++){
      #pragma unroll
      for (int r=0;r<4;r++){
        int row = m0 + wr*64 + mi*16 + (lane>>4)*4 + r;
        xwp[row*G4_ + p] = f2bf(acc[mi][ni][r] + bv);
      }
    }
  }
}

// ---------------------------------------------------------------------------
// Kernel 3: persistent cooperative LSTM scan + final h@W_lin+b_lin.
// 256 blocks x 256 threads. Block owns 4 h-cols (16 gate-cols).
// h transported via relaxed agent-scope (sc1) atomics -> NO agent fences,
// no buffer_wbl2/buffer_inv per step; barrier = distributed epoch flags.
// ---------------------------------------------------------------------------
__global__ __launch_bounds__(256, 1) void k_lstm(
    const unsigned short* __restrict__ xwp, unsigned short* __restrict__ hbuf,
    int* __restrict__ flags,
    const float* __restrict__ Wh, const float* __restrict__ Wc,
    const float* __restrict__ Wlin, const float* __restrict__ blin,
    float* __restrict__ out)
{
  __shared__ float xw_lds[64][16];
  __shared__ float gbuf[64][17];
  __shared__ unsigned short hstage[64][4];
  __shared__ float red[256];
  const int tid  = threadIdx.x;
  const int lane = tid & 63;
  const int w    = tid >> 6;
  const int phys = blockIdx.x;
  const int blk  = (phys & 7)*32 + (phys >> 3);  // XCD-grouped logical block id
  const int c0   = blk * 4;                      // first owned h-column

  // Pack Wh[:, 16 gate cols] into 32 register B-fragments (bf16).
  // B layout: n=lane&15 (local col = gate*4+within), k=(lane>>4)*8+j
  short8 wfrag[32];
  {
    const int ncol = lane & 15;
    const int gcol = (ncol >> 2)*HS_ + c0 + (ncol & 3);
    const int kr0  = (lane >> 4) * 8;
    #pragma unroll
    for (int ks=0; ks<32; ks++){
      short8 v;
      #pragma unroll
      for (int j=0;j<8;j++)
        v[j] = (short)f2bf(Wh[(ks*32 + kr0 + j)*G4_ + gcol]);
      wfrag[ks] = v;
    }
  }

  // Per-thread elementwise assignment: (batch row, owned col)
  const int erow = tid >> 2, ej = tid & 3;
  const int hcol = c0 + ej;
  const float wc0 = Wc[hcol], wc1 = Wc[HS_ + hcol], wc2 = Wc[2*HS_ + hcol];
  float c_reg = 0.f;

  // A-fragment addressing: row = batch (wave covers 16 rows), k contiguous 8
  const int arow = w*16 + (lane & 15);
  const int qb   = (lane >> 4) * 2;             // 8B-unit offset within row
  const int xr = tid & 63, xg = tid >> 6;       // xW loader mapping

  for (int t=0; t<S_; t++){
    const unsigned short* hin  = hbuf + (t & 1)      * B_ * HS_;
    unsigned short*       hout = hbuf + ((t+1) & 1)  * B_ * HS_;

    // Load this step's xW chunk (16 bf16 per row, 8B per thread) into LDS
    {
      ushort4 v = *(const ushort4*)(xwp + (xr*S_ + t)*G4_ + blk*16 + xg*4);
      xw_lds[xr][xg*4+0] = bf2f(v.x); xw_lds[xr][xg*4+1] = bf2f(v.y);
      xw_lds[xr][xg*4+2] = bf2f(v.z); xw_lds[xr][xg*4+3] = bf2f(v.w);
    }

    // h @ Wh_slice : [64x1024]@[1024x16], 32 MFMAs over 4 accumulator chains.
    // A fragments read with sc1 atomics (coherence point; local L2 untouched).
    floatx4 a0 = (floatx4){0.f,0.f,0.f,0.f}, a1 = a0, a2 = a0, a3 = a0;
    const unsigned long long* hq = (const unsigned long long*)(hin + arow*HS_);
    #pragma unroll
    for (int ks=0; ks<32; ks+=4){
      short8 f0 = ldfrag_sc1(hq + (ks+0)*8 + qb);
      short8 f1 = ldfrag_sc1(hq + (ks+1)*8 + qb);
      short8 f2 = ldfrag_sc1(hq + (ks+2)*8 + qb);
      short8 f3 = ldfrag_sc1(hq + (ks+3)*8 + qb);
      a0 = __builtin_amdgcn_mfma_f32_16x16x32_bf16(f0, wfrag[ks+0], a0, 0,0,0);
      a1 = __builtin_amdgcn_mfma_f32_16x16x32_bf16(f1, wfrag[ks+1], a1, 0,0,0);
      a2 = __builtin_amdgcn_mfma_f32_16x16x32_bf16(f2, wfrag[ks+2], a2, 0,0,0);
      a3 = __builtin_amdgcn_mfma_f32_16x16x32_bf16(f3, wfrag[ks+3], a3, 0,0,0);
    }
    floatx4 acc = a0 + a1 + a2 + a3;

    // Scatter C to LDS: col=lane&15, row=w*16+(lane>>4)*4+r
    {
      const int gr = w*16 + (lane>>4)*4;
      const int gc = lane & 15;
      gbuf[gr+0][gc] = acc[0];
      gbuf[gr+1][gc] = acc[1];
      gbuf[gr+2][gc] = acc[2];
      gbuf[gr+3][gc] = acc[3];
    }
    __syncthreads();

    // Elementwise LSTM cell (fp32 state in registers; peephole uses OLD c)
    {
      float gi = gbuf[erow][ 0+ej] + xw_lds[erow][ 0+ej];
      float gf = gbuf[erow][ 4+ej] + xw_lds[erow][ 4+ej];
      float gg = gbuf[erow][ 8+ej] + xw_lds[erow][ 8+ej];
      float go = gbuf[erow][12+ej] + xw_lds[erow][12+ej];
      float iv = sigm_f(gi + c_reg*wc0);
      float fv = sigm_f(gf + c_reg*wc1);
      float gv = tanh_f(gg);
      float ov = sigm_f(go + c_reg*wc2);
      float cn = fv*c_reg + iv*gv;
      float hn = ov*tanh_f(cn);
      c_reg = cn;
      hstage[erow][ej] = f2bf(hn);
    }
    __syncthreads();

    // Wave 0: pack 4 bf16/row and store 8B via sc1 atomic (write-through to
    // coherence point -> visible to all XCDs without wbl2).
    if (w == 0){
      unsigned long long hv = *(const unsigned long long*)&hstage[lane][0];
      __hip_atomic_store((unsigned long long*)(hout + lane*HS_ + c0), hv,
                         __ATOMIC_RELAXED, __HIP_MEMORY_SCOPE_AGENT);
    }

    // Distributed epoch barrier: drain stores, publish arrival, poll all flags.
    __builtin_amdgcn_fence(__ATOMIC_RELEASE, "workgroup");   // compiler ordering (cheap: no cache ops)
    __builtin_amdgcn_s_waitcnt(0);                           // h stores acked at coherence point
    if (tid == 0)
      __hip_atomic_store(flags + phys*16, t+1, __ATOMIC_RELAXED, __HIP_MEMORY_SCOPE_AGENT);
    if (w == 0){
      const int fb = lane*4;
      for (;;){
        int v0 = __hip_atomic_load(flags + (fb+0)*16, __ATOMIC_RELAXED, __HIP_MEMORY_SCOPE_AGENT);
        int v1 = __hip_atomic_load(flags + (fb+1)*16, __ATOMIC_RELAXED, __HIP_MEMORY_SCOPE_AGENT);
        int v2 = __hip_atomic_load(flags + (fb+2)*16, __ATOMIC_RELAXED, __HIP_MEMORY_SCOPE_AGENT);
        int v3 = __hip_atomic_load(flags + (fb+3)*16, __ATOMIC_RELAXED, __HIP_MEMORY_SCOPE_AGENT);
        int ok = (v0 >= t+1) && (v1 >= t+1) && (v2 >= t+1) && (v3 >= t+1);
        if (__all(ok)) break;
        __builtin_amdgcn_s_sleep(2);
      }
    }
    __syncthreads();
    __builtin_amdgcn_fence(__ATOMIC_ACQUIRE, "workgroup");   // compiler ordering only
  }

  // Final: out[b][d] = sum_k h512[b][k]*Wlin[k][d] + blin[d]   (h512 in hbuf[0])
  {
    const int b  = phys >> 2;
    const int cg = phys & 3;
    const int cl = tid & 31, kc = tid >> 5;
    const int col = cg*32 + cl;
    const unsigned long long* hq2 = (const unsigned long long*)(hbuf + b*HS_);
    float s = 0.f;
    for (int q=0; q<32; q++){
      unsigned long long v = __hip_atomic_load(hq2 + kc*32 + q, __ATOMIC_RELAXED, __HIP_MEMORY_SCOPE_AGENT);
      int k = kc*128 + q*4;
      s += bf2f((unsigned short)(v      )) * Wlin[(k+0)*DIM_ + col];
      s += bf2f((unsigned short)(v >> 16)) * Wlin[(k+1)*DIM_ + col];
      s += bf2f((unsigned short)(v >> 32)) * Wlin[(k+2)*DIM_ + col];
      s += bf2f((unsigned short)(v >> 48)) * Wlin[(k+3)*DIM_ + col];
    }
    red[tid] = s;
    __syncthreads();
    if (tid < 32){
      float tot = blin[cg*32 + tid];
      #pragma unroll
      for (int q=0;q<8;q++) tot += red[q*32 + tid];
      out[b*DIM_ + cg*32 + tid] = tot;
    }
  }
}

// ---------------------------------------------------------------------------
extern "C" void kernel_launch(void* const* d_in, const int* in_sizes, int n_in,
                              void* d_out, int out_size, void* d_ws, size_t ws_size,
                              hipStream_t stream)
{
  (void)in_sizes; (void)n_in; (void)out_size; (void)ws_size;
  const float* ev   = (const float*)d_in[0];
  const float* vcp  = (const float*)d_in[1];
  const float* vnp  = (const float*)d_in[2];
  const float* Ve   = (const float*)d_in[3];
  const float* Vc   = (const float*)d_in[4];
  const float* Vn   = (const float*)d_in[5];
  const float* Wx   = (const float*)d_in[6];
  const float* Wh   = (const float*)d_in[7];
  const float* Wc   = (const float*)d_in[8];
  const float* bias = (const float*)d_in[9];
  const float* Wl   = (const float*)d_in[10];
  const float* bl   = (const float*)d_in[11];
  float* outp = (float*)d_out;

  // ws layout: x fp32 (64MB) | xWP bf16 (256MB) | h double-buffer (256KB) | flags (16KB)
  char* ws = (char*)d_ws;
  float*          xf   = (float*)ws;
  unsigned short* xwp  = (unsigned short*)(ws + (size_t)67108864);
  unsigned short* hbuf = (unsigned short*)(ws + (size_t)67108864 + (size_t)268435456);
  int* flags           = (int*)(ws + (size_t)67108864 + (size_t)268435456 + (size_t)262144);

  // h0 = 0 and epoch flags = 0 (ws is re-poisoned before every launch).
  // memset kernel's end-of-kernel release writes these back to the coherence
  // point, so sc1 reads in k_lstm see them.
  hipMemsetAsync(hbuf, 0, 262144 + 16384, stream);

  k_embed<<<dim3(1024), dim3(256), 0, stream>>>(ev, vcp, vnp, Ve, Vc, Vn, xf);
  k_xw<<<dim3(8192), dim3(256), 0, stream>>>(xf, Wx, bias, xwp);

  const unsigned short* a0 = xwp;
  unsigned short* a1 = hbuf;
  int* a2 = flags;
  const float* a3 = Wh; const float* a4 = Wc;
  const float* a5 = Wl; const float* a6 = bl;
  float* a7 = outp;
  void* args[] = {&a0, &a1, &a2, &a3, &a4, &a5, &a6, &a7};
  hipLaunchCooperativeKernel((void*)k_lstm, dim3(256), dim3(256), args, 0, stream);
}

// Round 4
// 7212.616 us; speedup vs baseline: 1.7617x; 1.0190x over previous
//
#include <hip/hip_runtime.h>

// Problem dims
#define HS_   1024
#define G4_   4096
#define EMB_  512
#define B_    64
#define S_    512
#define DIM_  128

typedef __attribute__((ext_vector_type(8))) short short8;
typedef __attribute__((ext_vector_type(4))) float floatx4;

__device__ __forceinline__ unsigned short f2bf(float f){
  union { float f; unsigned u; } v; v.f = f;
  unsigned r = v.u + 0x7FFFu + ((v.u >> 16) & 1u);   // RNE
  return (unsigned short)(r >> 16);
}
__device__ __forceinline__ float bf2f(unsigned short b){
  union { unsigned u; float f; } v; v.u = ((unsigned)b) << 16; return v.f;
}
// hi/lo split: f = bf2f(hi) + bf2f(lo) + O(f * 2^-18)
__device__ __forceinline__ void splitbf(float f, unsigned short& hi, unsigned short& lo){
  unsigned short h = f2bf(f);
  hi = h;
  lo = f2bf(f - bf2f(h));
}
__device__ __forceinline__ float sigm_f(float x){ return 1.0f/(1.0f + __expf(-x)); }
__device__ __forceinline__ float tanh_f(float x){ return 1.0f - 2.0f/(1.0f + __expf(2.0f*x)); }

// ---------------------------------------------------------------------------
// Kernel 1: x = event@Ve + 2*vc@Vc + 2*tanh(vn@Vn)  -> fp32 [32768][512]
// 128x128 tiles, split-bf16 3-pass 16x16x32 MFMA (~fp32 accuracy).
// ---------------------------------------------------------------------------
__global__ __launch_bounds__(256) void k_embed(
    const float* __restrict__ ev, const float* __restrict__ vcp, const float* __restrict__ vnp,
    const float* __restrict__ Ve, const float* __restrict__ Vc, const float* __restrict__ Vn,
    float* __restrict__ xout)
{
  __shared__ unsigned short a_hi[128][40], a_lo[128][40];
  __shared__ unsigned short b_hi[128][40], b_lo[128][40];   // transposed: [n][k]
  const int tid  = threadIdx.x;
  const int lane = tid & 63;
  const int w    = tid >> 6;
  const int wr = w >> 1, wc = w & 1;
  const int mt = blockIdx.x >> 2;
  const int nt = blockIdx.x & 3;
  const int m0 = mt * 128, n0 = nt * 128;
  const int fr = lane & 15;
  const int fk = (lane >> 4) * 8;

  floatx4 acc[4][4];
  #pragma unroll
  for (int i=0;i<4;i++)
    #pragma unroll
    for (int j=0;j<4;j++)
      acc[i][j] = (floatx4){0.f,0.f,0.f,0.f};

  auto do_stage = [&](const float* A, int lda, const float* Bm, int kBase, float bscale){
    __syncthreads();
    #pragma unroll
    for (int c=0;c<4;c++){
      int flat = tid*16 + c*4;
      int r = flat >> 5, kk = flat & 31;
      float4 v = *(const float4*)(A + (m0+r)*lda + kBase + kk);
      splitbf(v.x, a_hi[r][kk+0], a_lo[r][kk+0]);
      splitbf(v.y, a_hi[r][kk+1], a_lo[r][kk+1]);
      splitbf(v.z, a_hi[r][kk+2], a_lo[r][kk+2]);
      splitbf(v.w, a_hi[r][kk+3], a_lo[r][kk+3]);
    }
    #pragma unroll
    for (int c=0;c<4;c++){
      int flat = tid*16 + c*4;
      int k = flat >> 7, nn = flat & 127;
      float4 v = *(const float4*)(Bm + (kBase+k)*EMB_ + n0 + nn);
      splitbf(v.x * bscale, b_hi[nn+0][k], b_lo[nn+0][k]);
      splitbf(v.y * bscale, b_hi[nn+1][k], b_lo[nn+1][k]);
      splitbf(v.z * bscale, b_hi[nn+2][k], b_lo[nn+2][k]);
      splitbf(v.w * bscale, b_hi[nn+3][k], b_lo[nn+3][k]);
    }
    __syncthreads();
    short8 ah[4], al[4], bh[4], bl[4];
    #pragma unroll
    for (int mi=0;mi<4;mi++){
      ah[mi] = *(const short8*)&a_hi[wr*64 + mi*16 + fr][fk];
      al[mi] = *(const short8*)&a_lo[wr*64 + mi*16 + fr][fk];
    }
    #pragma unroll
    for (int ni=0;ni<4;ni++){
      bh[ni] = *(const short8*)&b_hi[wc*64 + ni*16 + fr][fk];
      bl[ni] = *(const short8*)&b_lo[wc*64 + ni*16 + fr][fk];
    }
    #pragma unroll
    for (int mi=0;mi<4;mi++)
      #pragma unroll
      for (int ni=0;ni<4;ni++){
        floatx4 t = acc[mi][ni];
        t = __builtin_amdgcn_mfma_f32_16x16x32_bf16(al[mi], bh[ni], t, 0, 0, 0);
        t = __builtin_amdgcn_mfma_f32_16x16x32_bf16(ah[mi], bl[ni], t, 0, 0, 0);
        t = __builtin_amdgcn_mfma_f32_16x16x32_bf16(ah[mi], bh[ni], t, 0, 0, 0);
        acc[mi][ni] = t;
      }
  };

  do_stage(vnp, 64, Vn, 0, 1.f);
  do_stage(vnp, 64, Vn, 32, 1.f);
  #pragma unroll
  for (int mi=0;mi<4;mi++)
    #pragma unroll
    for (int ni=0;ni<4;ni++)
      #pragma unroll
      for (int r=0;r<4;r++)
        acc[mi][ni][r] = 2.f * tanh_f(acc[mi][ni][r]);
  for (int ks=0; ks<32; ks++) do_stage(ev, 1024, Ve, ks*32, 1.f);
  for (int ks=0; ks<16; ks++) do_stage(vcp, 512, Vc, ks*32, 2.f);

  #pragma unroll
  for (int mi=0;mi<4;mi++)
    #pragma unroll
    for (int ni=0;ni<4;ni++){
      int col = n0 + wc*64 + ni*16 + fr;
      #pragma unroll
      for (int r=0;r<4;r++){
        int row = m0 + wr*64 + mi*16 + (lane>>4)*4 + r;
        xout[row*EMB_ + col] = acc[mi][ni][r];
      }
    }
}

// ---------------------------------------------------------------------------
// Kernel 2: xW = x@Wx + bias -> bf16, COLUMN-PERMUTED layout:
//   p = blk*16 + gate*4 + within,  source col n(p) = gate*1024 + blk*4 + within
// ---------------------------------------------------------------------------
__global__ __launch_bounds__(256) void k_xw(
    const float* __restrict__ x, const float* __restrict__ Wx,
    const float* __restrict__ bias, unsigned short* __restrict__ xwp)
{
  __shared__ unsigned short a_hi[128][40], a_lo[128][40];
  __shared__ unsigned short b_hi[128][40], b_lo[128][40];
  const int tid  = threadIdx.x;
  const int lane = tid & 63;
  const int w    = tid >> 6;
  const int wr = w >> 1, wc = w & 1;
  const int mt = blockIdx.x >> 5;
  const int nt = blockIdx.x & 31;
  const int m0 = mt * 128, p0 = nt * 128;
  const int fr = lane & 15;
  const int fk = (lane >> 4) * 8;

  floatx4 acc[4][4];
  #pragma unroll
  for (int i=0;i<4;i++)
    #pragma unroll
    for (int j=0;j<4;j++)
      acc[i][j] = (floatx4){0.f,0.f,0.f,0.f};

  for (int ks=0; ks<16; ks++){
    const int kBase = ks*32;
    __syncthreads();
    #pragma unroll
    for (int c=0;c<4;c++){
      int flat = tid*16 + c*4;
      int r = flat >> 5, kk = flat & 31;
      float4 v = *(const float4*)(x + (m0+r)*EMB_ + kBase + kk);
      splitbf(v.x, a_hi[r][kk+0], a_lo[r][kk+0]);
      splitbf(v.y, a_hi[r][kk+1], a_lo[r][kk+1]);
      splitbf(v.z, a_hi[r][kk+2], a_lo[r][kk+2]);
      splitbf(v.w, a_hi[r][kk+3], a_lo[r][kk+3]);
    }
    #pragma unroll
    for (int c=0;c<4;c++){
      int flat = tid*16 + c*4;
      int k = flat >> 7, pc = flat & 127;
      int p = p0 + pc;
      int nbase = ((p>>2)&3)*HS_ + (p>>4)*4;
      float4 v = *(const float4*)(Wx + (kBase+k)*G4_ + nbase);
      splitbf(v.x, b_hi[pc+0][k], b_lo[pc+0][k]);
      splitbf(v.y, b_hi[pc+1][k], b_lo[pc+1][k]);
      splitbf(v.z, b_hi[pc+2][k], b_lo[pc+2][k]);
      splitbf(v.w, b_hi[pc+3][k], b_lo[pc+3][k]);
    }
    __syncthreads();
    short8 ah[4], al[4], bh[4], bl[4];
    #pragma unroll
    for (int mi=0;mi<4;mi++){
      ah[mi] = *(const short8*)&a_hi[wr*64 + mi*16 + fr][fk];
      al[mi] = *(const short8*)&a_lo[wr*64 + mi*16 + fr][fk];
    }
    #pragma unroll
    for (int ni=0;ni<4;ni++){
      bh[ni] = *(const short8*)&b_hi[wc*64 + ni*16 + fr][fk];
      bl[ni] = *(const short8*)&b_lo[wc*64 + ni*16 + fr][fk];
    }
    #pragma unroll
    for (int mi=0;mi<4;mi++)
      #pragma unroll
      for (int ni=0;ni<4;ni++){
        floatx4 t = acc[mi][ni];
        t = __builtin_amdgcn_mfma_f32_16x16x32_bf16(al[mi], bh[ni], t, 0, 0, 0);
        t = __builtin_amdgcn_mfma_f32_16x16x32_bf16(ah[mi], bl[ni], t, 0, 0, 0);
        t = __builtin_amdgcn_mfma_f32_16x16x32_bf16(ah[mi], bh[ni], t, 0, 0, 0);
        acc[mi][ni] = t;
      }
  }

  #pragma unroll
  for (int ni=0;ni<4;ni++){
    int p = p0 + wc*64 + ni*16 + fr;
    int n = ((p>>2)&3)*HS_ + (p>>4)*4 + (p&3);
    float bv = bias[n];
    #pragma unroll
    for (int mi=0;mi<4;mi++){
      #pragma unroll
      for (int r=0;r<4;r++){
        int row = m0 + wr*64 + mi*16 + (lane>>4)*4 + r;
        xwp[row*G4_ + p] = f2bf(acc[mi][ni][r] + bv);
      }
    }
  }
}

// ---------------------------------------------------------------------------
// Kernel 3: persistent cooperative LSTM scan, 4 independent batch-groups.
// 256 blocks = 4 groups (16 batch rows each) x 64 col-blocks (64 gate-cols).
// h stores: sc1 (write-through to MALL). h loads: PLAIN (L2-cached); a
// per-step agent-acquire fence (buffer_inv) makes them fresh -> broadcast is
// served by each XCD's L2 after one MALL fetch per line.
// Barrier: per-group 64 distributed epoch flags (1 per lane, no RMW).
// ---------------------------------------------------------------------------
__global__ __launch_bounds__(256, 1) void k_lstm(
    const unsigned short* __restrict__ xwp, unsigned short* __restrict__ hbuf,
    int* __restrict__ flags,
    const float* __restrict__ Wh, const float* __restrict__ Wc,
    const float* __restrict__ Wlin, const float* __restrict__ blin,
    float* __restrict__ out)
{
  __shared__ float xw_lds[16][68];
  __shared__ float gbuf[16][68];
  __shared__ unsigned short hstage[16][16];
  __shared__ float red[256];
  const int tid  = threadIdx.x;
  const int lane = tid & 63;
  const int w    = tid >> 6;
  const int phys = blockIdx.x;
  const int grp  = (phys >> 3) & 3;              // batch group (8 blocks/XCD each)
  const int cb   = (phys & 7)*8 + (phys >> 5);   // col-block 0..63 (XCD-major)
  const int r0   = grp * 16;                     // first batch row
  const int p0   = cb * 64;                      // first permuted gate-col

  // Pack Wh[:, 16 gate cols of this wave] into 32 register B-fragments.
  // Wave w owns p_loc in [w*16, w*16+16): B layout n=lane&15, k=(lane>>4)*8+j
  short8 wfrag[32];
  {
    const int p    = p0 + w*16 + (lane & 15);
    const int gcol = ((p>>2)&3)*HS_ + (p>>4)*4 + (p&3);
    const int kr0  = (lane >> 4) * 8;
    #pragma unroll
    for (int ks=0; ks<32; ks++){
      short8 v;
      #pragma unroll
      for (int j=0;j<8;j++)
        v[j] = (short)f2bf(Wh[(ks*32 + kr0 + j)*G4_ + gcol]);
      wfrag[ks] = v;
    }
  }

  // Elementwise assignment: thread -> (local row, local h-col), 1 element
  const int erow = tid >> 4, ej = tid & 15;
  const int hcol = cb*16 + ej;
  const float wc0 = Wc[hcol], wc1 = Wc[HS_ + hcol], wc2 = Wc[2*HS_ + hcol];
  const int gidx = (ej >> 2)*16 + (ej & 3);      // gate-0 index into 64-wide row
  float c_reg = 0.f;

  // A-fragment addressing (same 16 rows for all 4 waves; L1-shared)
  const int aoff = (r0 + (lane & 15))*HS_ + (lane >> 4)*8;
  // xwp prefetch mapping: thread -> (row, 4-col chunk)
  const int prow = tid >> 4, pchunk = tid & 15;
  const unsigned short* xwbase = xwp + ((size_t)(r0 + prow)*S_)*G4_ + p0 + pchunk*4;

  // Prefetch step-0 xw chunk into registers
  ushort4 xwpre = *(const ushort4*)(xwbase);

  for (int t=0; t<S_; t++){
    const unsigned short* hin  = hbuf + (t & 1)      * B_ * HS_;
    unsigned short*       hout = hbuf + ((t+1) & 1)  * B_ * HS_;

    // Commit prefetched xw chunk to LDS; prefetch next step's into regs.
    xw_lds[prow][pchunk*4+0] = bf2f(xwpre.x);
    xw_lds[prow][pchunk*4+1] = bf2f(xwpre.y);
    xw_lds[prow][pchunk*4+2] = bf2f(xwpre.z);
    xw_lds[prow][pchunk*4+3] = bf2f(xwpre.w);
    if (t+1 < S_) xwpre = *(const ushort4*)(xwbase + (size_t)(t+1)*G4_);

    // h @ Wh_slice : [16x1024]@[1024x16] per wave, plain (L2-cached) A loads
    floatx4 a0 = (floatx4){0.f,0.f,0.f,0.f}, a1 = a0, a2 = a0, a3 = a0;
    const unsigned short* ap = hin + aoff;
    #pragma unroll
    for (int ks=0; ks<32; ks+=4){
      short8 f0 = *(const short8*)(ap + (ks+0)*32);
      short8 f1 = *(const short8*)(ap + (ks+1)*32);
      short8 f2 = *(const short8*)(ap + (ks+2)*32);
      short8 f3 = *(const short8*)(ap + (ks+3)*32);
      a0 = __builtin_amdgcn_mfma_f32_16x16x32_bf16(f0, wfrag[ks+0], a0, 0,0,0);
      a1 = __builtin_amdgcn_mfma_f32_16x16x32_bf16(f1, wfrag[ks+1], a1, 0,0,0);
      a2 = __builtin_amdgcn_mfma_f32_16x16x32_bf16(f2, wfrag[ks+2], a2, 0,0,0);
      a3 = __builtin_amdgcn_mfma_f32_16x16x32_bf16(f3, wfrag[ks+3], a3, 0,0,0);
    }
    floatx4 acc = a0 + a1 + a2 + a3;

    // Scatter C to LDS: local col = w*16 + (lane&15), local row=(lane>>4)*4+r
    {
      const int gr = (lane>>4)*4;
      const int gc = w*16 + (lane & 15);
      gbuf[gr+0][gc] = acc[0];
      gbuf[gr+1][gc] = acc[1];
      gbuf[gr+2][gc] = acc[2];
      gbuf[gr+3][gc] = acc[3];
    }
    __syncthreads();

    // Elementwise LSTM cell (fp32 state in registers; peephole uses OLD c)
    {
      float gi = gbuf[erow][gidx     ] + xw_lds[erow][gidx     ];
      float gf = gbuf[erow][gidx +  4] + xw_lds[erow][gidx +  4];
      float gg = gbuf[erow][gidx +  8] + xw_lds[erow][gidx +  8];
      float go = gbuf[erow][gidx + 12] + xw_lds[erow][gidx + 12];
      float iv = sigm_f(gi + c_reg*wc0);
      float fv = sigm_f(gf + c_reg*wc1);
      float gv = tanh_f(gg);
      float ov = sigm_f(go + c_reg*wc2);
      float cn = fv*c_reg + iv*gv;
      float hn = ov*tanh_f(cn);
      c_reg = cn;
      hstage[erow][ej] = f2bf(hn);
    }
    __syncthreads();

    // Wave 0: pack + 8B sc1 stores (write-through -> visible after readers' inv)
    if (w == 0){
      const int row = lane >> 2, q = lane & 3;
      unsigned long long hv = *(const unsigned long long*)&hstage[row][q*4];
      __hip_atomic_store((unsigned long long*)(hout + (r0+row)*HS_ + cb*16 + q*4),
                         hv, __ATOMIC_RELAXED, __HIP_MEMORY_SCOPE_AGENT);
    }

    // Per-group epoch barrier: drain stores, publish, poll 64 flags (1/lane)
    __builtin_amdgcn_s_waitcnt(0);
    if (tid == 0)
      __hip_atomic_store(flags + (grp*64 + cb)*16, t+1,
                         __ATOMIC_RELAXED, __HIP_MEMORY_SCOPE_AGENT);
    if (w == 0){
      const int* fp = flags + (grp*64 + lane)*16;
      for (;;){
        int v = __hip_atomic_load(fp, __ATOMIC_RELAXED, __HIP_MEMORY_SCOPE_AGENT);
        if (__all(v >= t+1)) break;
        __builtin_amdgcn_s_sleep(1);
      }
    }
    __syncthreads();
    __builtin_amdgcn_fence(__ATOMIC_ACQUIRE, "agent");  // buffer_inv: fresh h via L2
  }

  // Final: one (row, 32-col half) per block: out[row][ch*32+cl]
  {
    const int row = r0 + (cb & 15);
    const int ch  = cb >> 4;
    const int cl = tid & 31, kc = tid >> 5;
    const int col = ch*32 + cl;
    const unsigned short* hrow = hbuf + row*HS_;      // parity 0 after 512 steps
    float s = 0.f;
    for (int k = kc*128; k < kc*128 + 128; k++)
      s += bf2f(hrow[k]) * Wlin[k*DIM_ + col];
    red[tid] = s;
    __syncthreads();
    if (tid < 32){
      float tot = blin[ch*32 + tid];
      #pragma unroll
      for (int q=0;q<8;q++) tot += red[q*32 + tid];
      out[row*DIM_ + ch*32 + tid] = tot;
    }
  }
}

// ---------------------------------------------------------------------------
extern "C" void kernel_launch(void* const* d_in, const int* in_sizes, int n_in,
                              void* d_out, int out_size, void* d_ws, size_t ws_size,
                              hipStream_t stream)
{
  (void)in_sizes; (void)n_in; (void)out_size; (void)ws_size;
  const float* ev   = (const float*)d_in[0];
  const float* vcp  = (const float*)d_in[1];
  const float* vnp  = (const float*)d_in[2];
  const float* Ve   = (const float*)d_in[3];
  const float* Vc   = (const float*)d_in[4];
  const float* Vn   = (const float*)d_in[5];
  const float* Wx   = (const float*)d_in[6];
  const float* Wh   = (const float*)d_in[7];
  const float* Wc   = (const float*)d_in[8];
  const float* bias = (const float*)d_in[9];
  const float* Wl   = (const float*)d_in[10];
  const float* bl   = (const float*)d_in[11];
  float* outp = (float*)d_out;

  // ws layout: x fp32 (64MB) | xWP bf16 (256MB) | h double-buffer (256KB) | flags (16KB)
  char* ws = (char*)d_ws;
  float*          xf   = (float*)ws;
  unsigned short* xwp  = (unsigned short*)(ws + (size_t)67108864);
  unsigned short* hbuf = (unsigned short*)(ws + (size_t)67108864 + (size_t)268435456);
  int* flags           = (int*)(ws + (size_t)67108864 + (size_t)268435456 + (size_t)262144);

  // h0 = 0 and epoch flags = 0 (dispatch-boundary cache ops make this visible)
  hipMemsetAsync(hbuf, 0, 262144 + 16384, stream);

  k_embed<<<dim3(1024), dim3(256), 0, stream>>>(ev, vcp, vnp, Ve, Vc, Vn, xf);
  k_xw<<<dim3(8192), dim3(256), 0, stream>>>(xf, Wx, bias, xwp);

  const unsigned short* a0 = xwp;
  unsigned short* a1 = hbuf;
  int* a2 = flags;
  const float* a3 = Wh; const float* a4 = Wc;
  const float* a5 = Wl; const float* a6 = bl;
  float* a7 = outp;
  void* args[] = {&a0, &a1, &a2, &a3, &a4, &a5, &a6, &a7};
  hipLaunchCooperativeKernel((void*)k_lstm, dim3(256), dim3(256), args, 0, stream);
}

// Round 5
// 6671.579 us; speedup vs baseline: 1.9045x; 1.0811x over previous
//
#include <hip/hip_runtime.h>

// Problem dims
#define HS_   1024
#define G4_   4096
#define EMB_  512
#define B_    64
#define S_    512
#define DIM_  128

typedef __attribute__((ext_vector_type(8))) short short8;
typedef __attribute__((ext_vector_type(4))) float floatx4;

__device__ __forceinline__ unsigned short f2bf(float f){
  union { float f; unsigned u; } v; v.f = f;
  unsigned r = v.u + 0x7FFFu + ((v.u >> 16) & 1u);   // RNE
  return (unsigned short)(r >> 16);
}
__device__ __forceinline__ float bf2f(unsigned short b){
  union { unsigned u; float f; } v; v.u = ((unsigned)b) << 16; return v.f;
}
// hi/lo split: f = bf2f(hi) + bf2f(lo) + O(f * 2^-18)
__device__ __forceinline__ void splitbf(float f, unsigned short& hi, unsigned short& lo){
  unsigned short h = f2bf(f);
  hi = h;
  lo = f2bf(f - bf2f(h));
}
__device__ __forceinline__ float sigm_f(float x){ return 1.0f/(1.0f + __expf(-x)); }
__device__ __forceinline__ float tanh_f(float x){ return 1.0f - 2.0f/(1.0f + __expf(2.0f*x)); }

// ---------------------------------------------------------------------------
// Kernel 1: x = event@Ve + 2*vc@Vc + 2*tanh(vn@Vn)  -> fp32 [32768][512]
// 128x128 tiles, split-bf16 3-pass 16x16x32 MFMA (~fp32 accuracy).
// ---------------------------------------------------------------------------
__global__ __launch_bounds__(256) void k_embed(
    const float* __restrict__ ev, const float* __restrict__ vcp, const float* __restrict__ vnp,
    const float* __restrict__ Ve, const float* __restrict__ Vc, const float* __restrict__ Vn,
    float* __restrict__ xout)
{
  __shared__ unsigned short a_hi[128][40], a_lo[128][40];
  __shared__ unsigned short b_hi[128][40], b_lo[128][40];   // transposed: [n][k]
  const int tid  = threadIdx.x;
  const int lane = tid & 63;
  const int w    = tid >> 6;
  const int wr = w >> 1, wc = w & 1;
  const int mt = blockIdx.x >> 2;
  const int nt = blockIdx.x & 3;
  const int m0 = mt * 128, n0 = nt * 128;
  const int fr = lane & 15;
  const int fk = (lane >> 4) * 8;

  floatx4 acc[4][4];
  #pragma unroll
  for (int i=0;i<4;i++)
    #pragma unroll
    for (int j=0;j<4;j++)
      acc[i][j] = (floatx4){0.f,0.f,0.f,0.f};

  auto do_stage = [&](const float* A, int lda, const float* Bm, int kBase, float bscale){
    __syncthreads();
    #pragma unroll
    for (int c=0;c<4;c++){
      int flat = tid*16 + c*4;
      int r = flat >> 5, kk = flat & 31;
      float4 v = *(const float4*)(A + (m0+r)*lda + kBase + kk);
      splitbf(v.x, a_hi[r][kk+0], a_lo[r][kk+0]);
      splitbf(v.y, a_hi[r][kk+1], a_lo[r][kk+1]);
      splitbf(v.z, a_hi[r][kk+2], a_lo[r][kk+2]);
      splitbf(v.w, a_hi[r][kk+3], a_lo[r][kk+3]);
    }
    #pragma unroll
    for (int c=0;c<4;c++){
      int flat = tid*16 + c*4;
      int k = flat >> 7, nn = flat & 127;
      float4 v = *(const float4*)(Bm + (kBase+k)*EMB_ + n0 + nn);
      splitbf(v.x * bscale, b_hi[nn+0][k], b_lo[nn+0][k]);
      splitbf(v.y * bscale, b_hi[nn+1][k], b_lo[nn+1][k]);
      splitbf(v.z * bscale, b_hi[nn+2][k], b_lo[nn+2][k]);
      splitbf(v.w * bscale, b_hi[nn+3][k], b_lo[nn+3][k]);
    }
    __syncthreads();
    short8 ah[4], al[4], bh[4], bl[4];
    #pragma unroll
    for (int mi=0;mi<4;mi++){
      ah[mi] = *(const short8*)&a_hi[wr*64 + mi*16 + fr][fk];
      al[mi] = *(const short8*)&a_lo[wr*64 + mi*16 + fr][fk];
    }
    #pragma unroll
    for (int ni=0;ni<4;ni++){
      bh[ni] = *(const short8*)&b_hi[wc*64 + ni*16 + fr][fk];
      bl[ni] = *(const short8*)&b_lo[wc*64 + ni*16 + fr][fk];
    }
    #pragma unroll
    for (int mi=0;mi<4;mi++)
      #pragma unroll
      for (int ni=0;ni<4;ni++){
        floatx4 t = acc[mi][ni];
        t = __builtin_amdgcn_mfma_f32_16x16x32_bf16(al[mi], bh[ni], t, 0, 0, 0);
        t = __builtin_amdgcn_mfma_f32_16x16x32_bf16(ah[mi], bl[ni], t, 0, 0, 0);
        t = __builtin_amdgcn_mfma_f32_16x16x32_bf16(ah[mi], bh[ni], t, 0, 0, 0);
        acc[mi][ni] = t;
      }
  };

  do_stage(vnp, 64, Vn, 0, 1.f);
  do_stage(vnp, 64, Vn, 32, 1.f);
  #pragma unroll
  for (int mi=0;mi<4;mi++)
    #pragma unroll
    for (int ni=0;ni<4;ni++)
      #pragma unroll
      for (int r=0;r<4;r++)
        acc[mi][ni][r] = 2.f * tanh_f(acc[mi][ni][r]);
  for (int ks=0; ks<32; ks++) do_stage(ev, 1024, Ve, ks*32, 1.f);
  for (int ks=0; ks<16; ks++) do_stage(vcp, 512, Vc, ks*32, 2.f);

  #pragma unroll
  for (int mi=0;mi<4;mi++)
    #pragma unroll
    for (int ni=0;ni<4;ni++){
      int col = n0 + wc*64 + ni*16 + fr;
      #pragma unroll
      for (int r=0;r<4;r++){
        int row = m0 + wr*64 + mi*16 + (lane>>4)*4 + r;
        xout[row*EMB_ + col] = acc[mi][ni][r];
      }
    }
}

// ---------------------------------------------------------------------------
// Kernel 2: xW = x@Wx + bias -> bf16, COLUMN-PERMUTED layout:
//   p = blk*16 + gate*4 + within,  source col n(p) = gate*1024 + blk*4 + within
// ---------------------------------------------------------------------------
__global__ __launch_bounds__(256) void k_xw(
    const float* __restrict__ x, const float* __restrict__ Wx,
    const float* __restrict__ bias, unsigned short* __restrict__ xwp)
{
  __shared__ unsigned short a_hi[128][40], a_lo[128][40];
  __shared__ unsigned short b_hi[128][40], b_lo[128][40];
  const int tid  = threadIdx.x;
  const int lane = tid & 63;
  const int w    = tid >> 6;
  const int wr = w >> 1, wc = w & 1;
  const int mt = blockIdx.x >> 5;
  const int nt = blockIdx.x & 31;
  const int m0 = mt * 128, p0 = nt * 128;
  const int fr = lane & 15;
  const int fk = (lane >> 4) * 8;

  floatx4 acc[4][4];
  #pragma unroll
  for (int i=0;i<4;i++)
    #pragma unroll
    for (int j=0;j<4;j++)
      acc[i][j] = (floatx4){0.f,0.f,0.f,0.f};

  for (int ks=0; ks<16; ks++){
    const int kBase = ks*32;
    __syncthreads();
    #pragma unroll
    for (int c=0;c<4;c++){
      int flat = tid*16 + c*4;
      int r = flat >> 5, kk = flat & 31;
      float4 v = *(const float4*)(x + (m0+r)*EMB_ + kBase + kk);
      splitbf(v.x, a_hi[r][kk+0], a_lo[r][kk+0]);
      splitbf(v.y, a_hi[r][kk+1], a_lo[r][kk+1]);
      splitbf(v.z, a_hi[r][kk+2], a_lo[r][kk+2]);
      splitbf(v.w, a_hi[r][kk+3], a_lo[r][kk+3]);
    }
    #pragma unroll
    for (int c=0;c<4;c++){
      int flat = tid*16 + c*4;
      int k = flat >> 7, pc = flat & 127;
      int p = p0 + pc;
      int nbase = ((p>>2)&3)*HS_ + (p>>4)*4;
      float4 v = *(const float4*)(Wx + (kBase+k)*G4_ + nbase);
      splitbf(v.x, b_hi[pc+0][k], b_lo[pc+0][k]);
      splitbf(v.y, b_hi[pc+1][k], b_lo[pc+1][k]);
      splitbf(v.z, b_hi[pc+2][k], b_lo[pc+2][k]);
      splitbf(v.w, b_hi[pc+3][k], b_lo[pc+3][k]);
    }
    __syncthreads();
    short8 ah[4], al[4], bh[4], bl[4];
    #pragma unroll
    for (int mi=0;mi<4;mi++){
      ah[mi] = *(const short8*)&a_hi[wr*64 + mi*16 + fr][fk];
      al[mi] = *(const short8*)&a_lo[wr*64 + mi*16 + fr][fk];
    }
    #pragma unroll
    for (int ni=0;ni<4;ni++){
      bh[ni] = *(const short8*)&b_hi[wc*64 + ni*16 + fr][fk];
      bl[ni] = *(const short8*)&b_lo[wc*64 + ni*16 + fr][fk];
    }
    #pragma unroll
    for (int mi=0;mi<4;mi++)
      #pragma unroll
      for (int ni=0;ni<4;ni++){
        floatx4 t = acc[mi][ni];
        t = __builtin_amdgcn_mfma_f32_16x16x32_bf16(al[mi], bh[ni], t, 0, 0, 0);
        t = __builtin_amdgcn_mfma_f32_16x16x32_bf16(ah[mi], bl[ni], t, 0, 0, 0);
        t = __builtin_amdgcn_mfma_f32_16x16x32_bf16(ah[mi], bh[ni], t, 0, 0, 0);
        acc[mi][ni] = t;
      }
  }

  #pragma unroll
  for (int ni=0;ni<4;ni++){
    int p = p0 + wc*64 + ni*16 + fr;
    int n = ((p>>2)&3)*HS_ + (p>>4)*4 + (p&3);
    float bv = bias[n];
    #pragma unroll
    for (int mi=0;mi<4;mi++){
      #pragma unroll
      for (int r=0;r<4;r++){
        int row = m0 + wr*64 + mi*16 + (lane>>4)*4 + r;
        xwp[row*G4_ + p] = f2bf(acc[mi][ni][r] + bv);
      }
    }
  }
}

// ---------------------------------------------------------------------------
// Kernel 3: persistent cooperative LSTM scan, 4 independent batch-groups.
// 256 blocks = 4 groups (16 batch rows each) x 64 col-blocks (64 gate-cols).
// h stores: sc1 write-through. h loads: plain + per-step agent-acquire inv.
// Barrier: two-hop leader barrier (arrive flags -> leader -> single go word)
// to keep fine-grained MALL poll traffic ~100x lower than all-poll-all.
// ---------------------------------------------------------------------------
__global__ __launch_bounds__(256, 1) void k_lstm(
    const unsigned short* __restrict__ xwp, unsigned short* __restrict__ hbuf,
    int* __restrict__ flags,
    const float* __restrict__ Wh, const float* __restrict__ Wc,
    const float* __restrict__ Wlin, const float* __restrict__ blin,
    float* __restrict__ out)
{
  __shared__ float xw_lds[16][68];
  __shared__ float gbuf[16][68];
  __shared__ unsigned short hstage[16][16];
  __shared__ float red[256];
  const int tid  = threadIdx.x;
  const int lane = tid & 63;
  const int w    = tid >> 6;
  const int phys = blockIdx.x;
  const int grp  = (phys >> 3) & 3;              // batch group (8 blocks/XCD each)
  const int cb   = (phys & 7)*8 + (phys >> 5);   // col-block 0..63 (XCD-major)
  const int r0   = grp * 16;                     // first batch row
  const int p0   = cb * 64;                      // first permuted gate-col
  int* const arrive = flags + (grp*64 + cb)*16;  // this block's arrive word
  int* const gowrd  = flags + (256 + grp)*16;    // per-group go word

  // Pack Wh[:, 16 gate cols of this wave] into 32 register B-fragments.
  short8 wfrag[32];
  {
    const int p    = p0 + w*16 + (lane & 15);
    const int gcol = ((p>>2)&3)*HS_ + (p>>4)*4 + (p&3);
    const int kr0  = (lane >> 4) * 8;
    #pragma unroll
    for (int ks=0; ks<32; ks++){
      short8 v;
      #pragma unroll
      for (int j=0;j<8;j++)
        v[j] = (short)f2bf(Wh[(ks*32 + kr0 + j)*G4_ + gcol]);
      wfrag[ks] = v;
    }
  }

  // Elementwise assignment: thread -> (local row, local h-col), 1 element
  const int erow = tid >> 4, ej = tid & 15;
  const int hcol = cb*16 + ej;
  const float wc0 = Wc[hcol], wc1 = Wc[HS_ + hcol], wc2 = Wc[2*HS_ + hcol];
  const int gidx = (ej >> 2)*16 + (ej & 3);      // gate-0 index into 64-wide row
  float c_reg = 0.f;

  // A-fragment addressing (same 16 rows for all 4 waves; L1-shared)
  const int aoff = (r0 + (lane & 15))*HS_ + (lane >> 4)*8;
  // xwp prefetch mapping: thread -> (row, 4-col chunk)
  const int prow = tid >> 4, pchunk = tid & 15;
  const unsigned short* xwbase = xwp + ((size_t)(r0 + prow)*S_)*G4_ + p0 + pchunk*4;

  // Prefetch step-0 xw chunk into registers
  ushort4 xwpre = *(const ushort4*)(xwbase);

  for (int t=0; t<S_; t++){
    const unsigned short* hin  = hbuf + (t & 1)      * B_ * HS_;
    unsigned short*       hout = hbuf + ((t+1) & 1)  * B_ * HS_;

    // Commit prefetched xw chunk to LDS
    xw_lds[prow][pchunk*4+0] = bf2f(xwpre.x);
    xw_lds[prow][pchunk*4+1] = bf2f(xwpre.y);
    xw_lds[prow][pchunk*4+2] = bf2f(xwpre.z);
    xw_lds[prow][pchunk*4+3] = bf2f(xwpre.w);

    // h @ Wh_slice : [16x1024]@[1024x16] per wave, plain (L2-cached) A loads
    floatx4 a0 = (floatx4){0.f,0.f,0.f,0.f}, a1 = a0, a2 = a0, a3 = a0;
    const unsigned short* ap = hin + aoff;
    #pragma unroll
    for (int ks=0; ks<32; ks+=4){
      short8 f0 = *(const short8*)(ap + (ks+0)*32);
      short8 f1 = *(const short8*)(ap + (ks+1)*32);
      short8 f2 = *(const short8*)(ap + (ks+2)*32);
      short8 f3 = *(const short8*)(ap + (ks+3)*32);
      a0 = __builtin_amdgcn_mfma_f32_16x16x32_bf16(f0, wfrag[ks+0], a0, 0,0,0);
      a1 = __builtin_amdgcn_mfma_f32_16x16x32_bf16(f1, wfrag[ks+1], a1, 0,0,0);
      a2 = __builtin_amdgcn_mfma_f32_16x16x32_bf16(f2, wfrag[ks+2], a2, 0,0,0);
      a3 = __builtin_amdgcn_mfma_f32_16x16x32_bf16(f3, wfrag[ks+3], a3, 0,0,0);
    }
    floatx4 acc = a0 + a1 + a2 + a3;

    // Scatter C to LDS: local col = w*16 + (lane&15), local row=(lane>>4)*4+r
    {
      const int gr = (lane>>4)*4;
      const int gc = w*16 + (lane & 15);
      gbuf[gr+0][gc] = acc[0];
      gbuf[gr+1][gc] = acc[1];
      gbuf[gr+2][gc] = acc[2];
      gbuf[gr+3][gc] = acc[3];
    }
    __syncthreads();

    // Elementwise LSTM cell (fp32 state in registers; peephole uses OLD c)
    {
      float gi = gbuf[erow][gidx     ] + xw_lds[erow][gidx     ];
      float gf = gbuf[erow][gidx +  4] + xw_lds[erow][gidx +  4];
      float gg = gbuf[erow][gidx +  8] + xw_lds[erow][gidx +  8];
      float go = gbuf[erow][gidx + 12] + xw_lds[erow][gidx + 12];
      float iv = sigm_f(gi + c_reg*wc0);
      float fv = sigm_f(gf + c_reg*wc1);
      float gv = tanh_f(gg);
      float ov = sigm_f(go + c_reg*wc2);
      float cn = fv*c_reg + iv*gv;
      float hn = ov*tanh_f(cn);
      c_reg = cn;
      hstage[erow][ej] = f2bf(hn);
    }
    __syncthreads();

    // Wave 0: pack + 8B sc1 stores (write-through -> visible after readers' inv)
    if (w == 0){
      const int row = lane >> 2, q = lane & 3;
      unsigned long long hv = *(const unsigned long long*)&hstage[row][q*4];
      __hip_atomic_store((unsigned long long*)(hout + (r0+row)*HS_ + cb*16 + q*4),
                         hv, __ATOMIC_RELAXED, __HIP_MEMORY_SCOPE_AGENT);
      __builtin_amdgcn_s_waitcnt(0);             // h stores acked at coherence point
      if (lane == 0)
        __hip_atomic_store(arrive, t+1, __ATOMIC_RELAXED, __HIP_MEMORY_SCOPE_AGENT);
    }

    // Prefetch next step's xw chunk AFTER arrive-store (overlaps the go-wait,
    // keeps its HBM-miss latency off the store->flag critical path).
    if (t+1 < S_) xwpre = *(const ushort4*)(xwbase + (size_t)(t+1)*G4_);

    // Leader (cb==0) wave 0: aggregate 64 arrive flags -> publish go word.
    if (cb == 0 && w == 0){
      const int* fp = flags + (grp*64 + lane)*16;
      for (;;){
        int v = __hip_atomic_load(fp, __ATOMIC_RELAXED, __HIP_MEMORY_SCOPE_AGENT);
        if (__all(v >= t+1)) break;
        __builtin_amdgcn_s_sleep(2);
      }
      if (lane == 0)
        __hip_atomic_store(gowrd, t+1, __ATOMIC_RELAXED, __HIP_MEMORY_SCOPE_AGENT);
    }
    // Everyone: single thread polls the single go word.
    if (tid == 0){
      for (;;){
        int v = __hip_atomic_load(gowrd, __ATOMIC_RELAXED, __HIP_MEMORY_SCOPE_AGENT);
        if (v >= t+1) break;
        __builtin_amdgcn_s_sleep(2);
      }
    }
    __syncthreads();
    __builtin_amdgcn_fence(__ATOMIC_ACQUIRE, "agent");  // buffer_inv: fresh h via L2
  }

  // Final: one (row, 32-col half) per block: out[row][ch*32+cl]
  {
    const int row = r0 + (cb & 15);
    const int ch  = cb >> 4;
    const int cl = tid & 31, kc = tid >> 5;
    const int col = ch*32 + cl;
    const unsigned short* hrow = hbuf + row*HS_;      // parity 0 after 512 steps
    float s = 0.f;
    for (int k = kc*128; k < kc*128 + 128; k++)
      s += bf2f(hrow[k]) * Wlin[k*DIM_ + col];
    red[tid] = s;
    __syncthreads();
    if (tid < 32){
      float tot = blin[ch*32 + tid];
      #pragma unroll
      for (int q=0;q<8;q++) tot += red[q*32 + tid];
      out[row*DIM_ + ch*32 + tid] = tot;
    }
  }
}

// ---------------------------------------------------------------------------
extern "C" void kernel_launch(void* const* d_in, const int* in_sizes, int n_in,
                              void* d_out, int out_size, void* d_ws, size_t ws_size,
                              hipStream_t stream)
{
  (void)in_sizes; (void)n_in; (void)out_size; (void)ws_size;
  const float* ev   = (const float*)d_in[0];
  const float* vcp  = (const float*)d_in[1];
  const float* vnp  = (const float*)d_in[2];
  const float* Ve   = (const float*)d_in[3];
  const float* Vc   = (const float*)d_in[4];
  const float* Vn   = (const float*)d_in[5];
  const float* Wx   = (const float*)d_in[6];
  const float* Wh   = (const float*)d_in[7];
  const float* Wc   = (const float*)d_in[8];
  const float* bias = (const float*)d_in[9];
  const float* Wl   = (const float*)d_in[10];
  const float* bl   = (const float*)d_in[11];
  float* outp = (float*)d_out;

  // ws layout: x fp32 (64MB) | xWP bf16 (256MB) | h double-buffer (256KB) | flags (32KB)
  char* ws = (char*)d_ws;
  float*          xf   = (float*)ws;
  unsigned short* xwp  = (unsigned short*)(ws + (size_t)67108864);
  unsigned short* hbuf = (unsigned short*)(ws + (size_t)67108864 + (size_t)268435456);
  int* flags           = (int*)(ws + (size_t)67108864 + (size_t)268435456 + (size_t)262144);

  // h0 = 0, arrive flags = 0, go words = 0
  hipMemsetAsync(hbuf, 0, 262144 + 32768, stream);

  k_embed<<<dim3(1024), dim3(256), 0, stream>>>(ev, vcp, vnp, Ve, Vc, Vn, xf);
  k_xw<<<dim3(8192), dim3(256), 0, stream>>>(xf, Wx, bias, xwp);

  const unsigned short* a0 = xwp;
  unsigned short* a1 = hbuf;
  int* a2 = flags;
  const float* a3 = Wh; const float* a4 = Wc;
  const float* a5 = Wl; const float* a6 = bl;
  float* a7 = outp;
  void* args[] = {&a0, &a1, &a2, &a3, &a4, &a5, &a6, &a7};
  hipLaunchCooperativeKernel((void*)k_lstm, dim3(256), dim3(256), args, 0, stream);
}